// Round 13
// baseline (99.130 us; speedup 1.0000x reference)
//
#include <hip/hip_runtime.h>
#include <hip/hip_bf16.h>

typedef unsigned short u16;
typedef __attribute__((ext_vector_type(8))) short bf16x8;
typedef __attribute__((ext_vector_type(4))) float f32x4;

#define BDIM 4096
#define DDIM 1024
#define UDIM 1024
#define NE 8
#define NDIM 8192    // U*E
#define NPAIR 28     // C(8,2) unordered expert pairs
#define PL_CAP 4160  // per-pair rowlist capacity (4096 + pad)
#define MAX_MT 92    // max total m-tiles: floor(4096/64) + 27 + 1

__device__ __forceinline__ u16 f2bf(float f) {
    unsigned int u = __float_as_uint(f);
    u += 0x7fffu + ((u >> 16) & 1u);   // round-to-nearest-even
    return (u16)(u >> 16);
}

__device__ __forceinline__ void gload_lds16(const u16* g, u16* lds) {
    __builtin_amdgcn_global_load_lds(
        (const __attribute__((address_space(1))) void*)g,
        (__attribute__((address_space(3))) void*)lds, 16, 0, 0);
}

// ================= prep (fused): mu->Wt transpose | gating + x->bf16 | se =================
__global__ __launch_bounds__(256) void prep_kernel(
    const float* __restrict__ mu, const float* __restrict__ x,
    const float* __restrict__ gk, const float* __restrict__ gb,
    const float* __restrict__ rho, const float* __restrict__ eps,
    u16* __restrict__ Wt, u16* __restrict__ xb,
    float* __restrict__ xsum, int4* __restrict__ pkb,
    float* __restrict__ se)
{
    __shared__ u16 tile[64 * 68];
    const int bx = blockIdx.x;
    const int tid = threadIdx.x;

    if (bx < 2048) {
        const int n0 = (bx & 127) << 6;
        const int d0 = (bx >> 7) << 6;
        const int nq = (tid & 15) << 2;
        const int dr = tid >> 4;             // 0..15
#pragma unroll
        for (int p = 0; p < 4; ++p) {
            int dl = p * 16 + dr;
            float4 v = *(const float4*)&mu[(size_t)(d0 + dl) * NDIM + n0 + nq];
            ushort4 o;
            o.x = f2bf(v.x); o.y = f2bf(v.y); o.z = f2bf(v.z); o.w = f2bf(v.w);
            *(uint2*)&tile[dl * 68 + nq] = *(uint2*)&o;   // ds_write_b64
        }
        __syncthreads();
#pragma unroll
        for (int issue = 0; issue < 2; ++issue) {
            int nloc = issue * 32 + (tid >> 3);
            int d8 = (tid & 7) * 8;
            uint4 o; u16* tp = (u16*)&o;
#pragma unroll
            for (int i = 0; i < 8; ++i) tp[i] = tile[(d8 + i) * 68 + nloc];
            *(uint4*)&Wt[(size_t)(n0 + nloc) * DDIM + d0 + d8] = o;
        }
    } else if (bx < 3072) {
        const int b = (bx - 2048) * 4 + (tid >> 6);
        const int lane = tid & 63;
        float acc[8] = {0.f,0.f,0.f,0.f,0.f,0.f,0.f,0.f};
        float xs = 0.f;
        const float4* x4 = (const float4*)&x[(size_t)b * DDIM];
        ushort4* xb4 = (ushort4*)&xb[(size_t)b * DDIM];
#pragma unroll
        for (int it = 0; it < 4; ++it) {
            int i4 = it * 64 + lane;
            float4 v = x4[i4];
            ushort4 o;
            o.x = f2bf(v.x); o.y = f2bf(v.y); o.z = f2bf(v.z); o.w = f2bf(v.w);
            xb4[i4] = o;
            xs += v.x + v.y + v.z + v.w;
            const float4* g4 = (const float4*)&gk[(size_t)i4 * 4 * NE];
#pragma unroll
            for (int j = 0; j < 4; ++j) {
                float xv = ((const float*)&v)[j];
                float4 ga = g4[j * 2], gc = g4[j * 2 + 1];
                acc[0] += xv * ga.x; acc[1] += xv * ga.y; acc[2] += xv * ga.z; acc[3] += xv * ga.w;
                acc[4] += xv * gc.x; acc[5] += xv * gc.y; acc[6] += xv * gc.z; acc[7] += xv * gc.w;
            }
        }
#pragma unroll
        for (int off = 32; off >= 1; off >>= 1) {
            xs += __shfl_xor(xs, off);
#pragma unroll
            for (int e = 0; e < 8; ++e) acc[e] += __shfl_xor(acc[e], off);
        }
        if (lane == 0) {
            float lg[8];
#pragma unroll
            for (int e = 0; e < 8; ++e) lg[e] = acc[e] + gb[e];
            int i1 = 0;
#pragma unroll
            for (int e = 1; e < 8; ++e) if (lg[e] > lg[i1]) i1 = e;  // first-occurrence argmax
            int i2 = (i1 == 0) ? 1 : 0;
#pragma unroll
            for (int e = 0; e < 8; ++e) {
                if (e == i1 || e == i2) continue;
                if (lg[e] > lg[i2]) i2 = e;
            }
            float p1 = 1.f / (1.f + expf(lg[i2] - lg[i1]));  // renorm top-2 softmax
            float p2 = 1.f - p1;
            xsum[b] = xs;
            pkb[b] = make_int4(i1, i2, __float_as_int(p1), __float_as_int(p2));
        }
    } else {
        int i = (bx - 3072) * 256 + tid;
        float r = rho[i];
        se[i] = log1pf(expf(r)) * eps[i];
    }
}

// ================= pairlist: compact rows per unordered expert pair (28 blocks) =================
__global__ __launch_bounds__(256) void pairlist_kernel(
    const int4* __restrict__ pkb, int* __restrict__ cnt,
    u16* __restrict__ plist)
{
    const int pid = blockIdx.x;
    int p = 0, rem = pid;                 // decode p<q triangular
    while (rem >= 7 - p) { rem -= 7 - p; ++p; }
    const int q = p + 1 + rem;

    const int tid = threadIdx.x;
    const int wv = tid >> 6, lane = tid & 63;
    __shared__ int wsum[4];
    __shared__ int sbase;
    if (tid == 0) sbase = 0;
    __syncthreads();
    u16* pl = plist + pid * PL_CAP;
    for (int chunk = 0; chunk < BDIM; chunk += 256) {
        int b = chunk + tid;
        int4 pk = pkb[b];
        int lo = min(pk.x, pk.y), hi = max(pk.x, pk.y);
        bool f = (lo == p) && (hi == q);
        unsigned long long m = __ballot(f);
        int prefix = __popcll(m & ((1ULL << lane) - 1ULL));
        if (lane == 0) wsum[wv] = __popcll(m);
        __syncthreads();
        int wbase = sbase;
        for (int w = 0; w < wv; ++w) wbase += wsum[w];
        if (f) pl[wbase + prefix] = (u16)b;
        __syncthreads();
        if (tid == 0) sbase += wsum[0] + wsum[1] + wsum[2] + wsum[3];
        __syncthreads();
    }
    int c = sbase;
    int pc = (c + 63) & ~63;
    for (int i = c + tid; i < pc; i += 256) pl[i] = (u16)0xFFFF;
    if (tid == 0) cnt[pid] = c;
}

// ================= pair GEMM: round-8 geometry + DEPTH-3 prefetch pipeline =================
// 64 rows x 64 u-cols x BOTH experts; T2 both-sides XOR swizzle (conflicts 0);
// plain stores, no atomics. Change vs round 8: triple-buffered LDS (72 KB,
// 2 blocks/CU) so the vmcnt wait targets loads issued TWO tile-steps earlier
// (~4000+ cyc) -- hides L2-miss/L3 latency that depth-2 left exposed.
__global__ __launch_bounds__(256, 2) void gemm_pair_kernel(
    const u16* __restrict__ Xb,      // [4096][1024] bf16
    const u16* __restrict__ Wt,      // [8192][1024] bf16, row n = u*8+e
    const int4* __restrict__ pkb,    // per-row (i1,i2,p1,p2)
    const float* __restrict__ xsum,  // [4096]
    const float* __restrict__ se,    // [8192]
    const float* __restrict__ biasv, // [8192]
    const int* __restrict__ cnt,     // [28]
    const u16* __restrict__ plist,   // [28][PL_CAP]
    float* __restrict__ y)           // [4096][1024]
{
    const int bid = blockIdx.x;
    const int ntile = bid & 15;       // 16 n-tiles of 64 cols
    const int t = bid >> 4;           // m-slot 0..MAX_MT-1
    int pid = 0, base = 0;
    for (; pid < NPAIR; ++pid) {
        int mt = (cnt[pid] + 63) >> 6;
        if (t < base + mt) break;
        base += mt;
    }
    if (pid >= NPAIR) return;
    const int m0 = (t - base) << 6;
    int p = 0, rem = pid;
    while (rem >= 7 - p) { rem -= 7 - p; ++p; }
    const int q = p + 1 + rem;
    const int u0 = ntile << 6;

    __shared__ u16 As[3][64 * 64];    // 24 KB
    __shared__ u16 Bp[3][64 * 64];    // 24 KB
    __shared__ u16 Bq[3][64 * 64];    // 24 KB

    const int tid  = threadIdx.x;
    const int lane = tid & 63;
    const int wid  = tid >> 6;
    const int wm = wid >> 1, wn = wid & 1;
    const int l15 = lane & 15;
    const int l4  = lane >> 4;

    const u16* __restrict__ rowl = plist + pid * PL_CAP + m0;
    const int stg_off = tid * 8;        // linear LDS dest (u16)
    const int sc = (((tid & 7) ^ ((tid >> 3) & 7))) * 8;  // source-side swizzle

    const u16* aP[2];
    const u16* bpP[2];
    const u16* bqP[2];
#pragma unroll
    for (int it = 0; it < 2; ++it) {
        int r = it * 32 + (tid >> 3);
        int rid = rowl[r];
        if (rid == 0xFFFF) rid = 0;     // padded slot: any valid row
        aP[it]  = Xb + (size_t)rid * DDIM + sc;
        bpP[it] = Wt + ((size_t)(u0 + r) * NE + p) * DDIM + sc;
        bqP[it] = Wt + ((size_t)(u0 + r) * NE + q) * DDIM + sc;
    }

#define STAGE(BUF, KK) do {                                     \
        gload_lds16(aP[0]  + (KK), &As[BUF][stg_off]);          \
        gload_lds16(aP[1]  + (KK), &As[BUF][2048 + stg_off]);   \
        gload_lds16(bpP[0] + (KK), &Bp[BUF][stg_off]);          \
        gload_lds16(bpP[1] + (KK), &Bp[BUF][2048 + stg_off]);   \
        gload_lds16(bqP[0] + (KK), &Bq[BUF][stg_off]);          \
        gload_lds16(bqP[1] + (KK), &Bq[BUF][2048 + stg_off]);   \
    } while (0)

    f32x4 accp[2][2] = {};
    f32x4 accq[2][2] = {};

    STAGE(0, 0);
    STAGE(1, 64);
    STAGE(2, 128);                      // 18 loads in flight (3 tiles deep)

    const int sw = l15 & 7;             // read-side swizzle key

#pragma unroll
    for (int t2 = 0; t2 < 16; ++t2) {
        const int cur = t2 % 3;
        if (t2 <= 13)      asm volatile("s_waitcnt vmcnt(12)" ::: "memory");
        else if (t2 == 14) asm volatile("s_waitcnt vmcnt(6)"  ::: "memory");
        else               asm volatile("s_waitcnt vmcnt(0)"  ::: "memory");
        __builtin_amdgcn_s_barrier();          // tile t2 resident
        __builtin_amdgcn_sched_barrier(0);
#pragma unroll
        for (int k2 = 0; k2 < 2; ++k2) {
            const int cx = ((k2 * 4 + l4) ^ sw) * 8;
            bf16x8 av[2], bpv[2], bqv[2];
#pragma unroll
            for (int m = 0; m < 2; ++m)
                av[m] = *(const bf16x8*)&As[cur][(wm * 32 + m * 16 + l15) * 64 + cx];
#pragma unroll
            for (int n = 0; n < 2; ++n) {
                bpv[n] = *(const bf16x8*)&Bp[cur][(wn * 32 + n * 16 + l15) * 64 + cx];
                bqv[n] = *(const bf16x8*)&Bq[cur][(wn * 32 + n * 16 + l15) * 64 + cx];
            }
#pragma unroll
            for (int m = 0; m < 2; ++m)
#pragma unroll
                for (int n = 0; n < 2; ++n) {
                    accp[m][n] = __builtin_amdgcn_mfma_f32_16x16x32_bf16(av[m], bpv[n], accp[m][n], 0, 0, 0);
                    accq[m][n] = __builtin_amdgcn_mfma_f32_16x16x32_bf16(av[m], bqv[n], accq[m][n], 0, 0, 0);
                }
        }
        __builtin_amdgcn_sched_barrier(0);
        __builtin_amdgcn_s_barrier();          // all waves done with buf[cur]
        if (t2 < 13) STAGE(cur, (t2 + 3) * 64);  // refill freed buffer, 3 ahead
    }
#undef STAGE

    // Epilogue: y[b,u] = wp*(dot_p + xs*se_p + bias_p) + wq*(dot_q + xs*se_q + bias_q)
    // C/D layout: col=lane&15 (u), row=(lane>>4)*4+jj.
    float sep_[2], seq_[2], bip_[2], biq_[2];
#pragma unroll
    for (int n = 0; n < 2; ++n) {
        int u = u0 + wn * 32 + n * 16 + l15;
        sep_[n] = se[u * NE + p];    seq_[n] = se[u * NE + q];
        bip_[n] = biasv[u * NE + p]; biq_[n] = biasv[u * NE + q];
    }
#pragma unroll
    for (int m = 0; m < 2; ++m) {
#pragma unroll
        for (int jj = 0; jj < 4; ++jj) {
            int r_loc = wm * 32 + m * 16 + l4 * 4 + jj;
            u16 b16 = rowl[r_loc];
            if (b16 == (u16)0xFFFF) continue;
            int b = (int)b16;
            int4 pk = pkb[b];
            float wp, wq;
            if (pk.x == p) { wp = __int_as_float(pk.z); wq = __int_as_float(pk.w); }
            else           { wp = __int_as_float(pk.w); wq = __int_as_float(pk.z); }
            float xs = xsum[b];
            float* yrow = &y[(size_t)b * UDIM];
#pragma unroll
            for (int n = 0; n < 2; ++n) {
                int u = u0 + wn * 32 + n * 16 + l15;
                float val = wp * (accp[m][n][jj] + xs * sep_[n] + bip_[n])
                          + wq * (accq[m][n][jj] + xs * seq_[n] + biq_[n]);
                yrow[u] = val;
            }
        }
    }
}

extern "C" void kernel_launch(void* const* d_in, const int* in_sizes, int n_in,
                              void* d_out, int out_size, void* d_ws, size_t ws_size,
                              hipStream_t stream) {
    const float* x    = (const float*)d_in[0];
    const float* mu   = (const float*)d_in[1];
    const float* rho  = (const float*)d_in[2];
    const float* bias = (const float*)d_in[3];
    const float* gk   = (const float*)d_in[4];
    const float* gb   = (const float*)d_in[5];
    const float* eps  = (const float*)d_in[6];
    float* y = (float*)d_out;

    char* ws = (char*)d_ws;
    u16*   Wt   = (u16*)ws;                       // 16,777,216
    u16*   xb   = (u16*)(ws + 16777216);          //  8,388,608 -> 25165824
    float* xsp  = (float*)(ws + 25165824);        //     16,384 -> 25182208
    float* sep  = (float*)(ws + 25182208);        //     32,768 -> 25214976
    int*   cnt  = (int*)(ws + 25214976);          //        128 -> 25215104
    int4*  pkb  = (int4*)(ws + 25215104);         //     65,536 -> 25280640
    u16*   prl  = (u16*)(ws + 25280640);          //    232,960 -> 25513600
    if (ws_size < 25513600) return;

    prep_kernel<<<dim3(3104), dim3(256), 0, stream>>>(
        mu, x, gk, gb, rho, eps, Wt, xb, xsp, pkb, sep);
    pairlist_kernel<<<dim3(NPAIR), dim3(256), 0, stream>>>(pkb, cnt, prl);
    gemm_pair_kernel<<<dim3(MAX_MT * 16), dim3(256), 0, stream>>>(
        xb, Wt, pkb, xsp, sep, bias, cnt, prl, y);
}

// Round 14
// 89.654 us; speedup vs baseline: 1.1057x; 1.1057x over previous
//
#include <hip/hip_runtime.h>
#include <hip/hip_bf16.h>

typedef unsigned short u16;
typedef __attribute__((ext_vector_type(8))) short bf16x8;
typedef __attribute__((ext_vector_type(4))) float f32x4;

#define BDIM 4096
#define DDIM 1024
#define UDIM 1024
#define NE 8
#define NDIM 8192    // U*E
#define NPAIR 28     // C(8,2) unordered expert pairs
#define PL_CAP 4160  // per-pair rowlist capacity (4096 + pad)
#define MAX_MT 92    // max total m-tiles: floor(4096/64) + 27 + 1

__device__ __forceinline__ u16 f2bf(float f) {
    unsigned int u = __float_as_uint(f);
    u += 0x7fffu + ((u >> 16) & 1u);   // round-to-nearest-even
    return (u16)(u >> 16);
}

__device__ __forceinline__ void gload_lds16(const u16* g, u16* lds) {
    __builtin_amdgcn_global_load_lds(
        (const __attribute__((address_space(1))) void*)g,
        (__attribute__((address_space(3))) void*)lds, 16, 0, 0);
}

// ================= prep (fused): mu->Wt transpose | gating + x->bf16 | se =================
__global__ __launch_bounds__(256) void prep_kernel(
    const float* __restrict__ mu, const float* __restrict__ x,
    const float* __restrict__ gk, const float* __restrict__ gb,
    const float* __restrict__ rho, const float* __restrict__ eps,
    u16* __restrict__ Wt, u16* __restrict__ xb,
    float* __restrict__ xsum, int4* __restrict__ pkb,
    float* __restrict__ se)
{
    __shared__ u16 tile[64 * 68];
    const int bx = blockIdx.x;
    const int tid = threadIdx.x;

    if (bx < 2048) {
        const int n0 = (bx & 127) << 6;
        const int d0 = (bx >> 7) << 6;
        const int nq = (tid & 15) << 2;
        const int dr = tid >> 4;             // 0..15
#pragma unroll
        for (int p = 0; p < 4; ++p) {
            int dl = p * 16 + dr;
            float4 v = *(const float4*)&mu[(size_t)(d0 + dl) * NDIM + n0 + nq];
            ushort4 o;
            o.x = f2bf(v.x); o.y = f2bf(v.y); o.z = f2bf(v.z); o.w = f2bf(v.w);
            *(uint2*)&tile[dl * 68 + nq] = *(uint2*)&o;   // ds_write_b64
        }
        __syncthreads();
#pragma unroll
        for (int issue = 0; issue < 2; ++issue) {
            int nloc = issue * 32 + (tid >> 3);
            int d8 = (tid & 7) * 8;
            uint4 o; u16* tp = (u16*)&o;
#pragma unroll
            for (int i = 0; i < 8; ++i) tp[i] = tile[(d8 + i) * 68 + nloc];
            *(uint4*)&Wt[(size_t)(n0 + nloc) * DDIM + d0 + d8] = o;
        }
    } else if (bx < 3072) {
        const int b = (bx - 2048) * 4 + (tid >> 6);
        const int lane = tid & 63;
        float acc[8] = {0.f,0.f,0.f,0.f,0.f,0.f,0.f,0.f};
        float xs = 0.f;
        const float4* x4 = (const float4*)&x[(size_t)b * DDIM];
        ushort4* xb4 = (ushort4*)&xb[(size_t)b * DDIM];
#pragma unroll
        for (int it = 0; it < 4; ++it) {
            int i4 = it * 64 + lane;
            float4 v = x4[i4];
            ushort4 o;
            o.x = f2bf(v.x); o.y = f2bf(v.y); o.z = f2bf(v.z); o.w = f2bf(v.w);
            xb4[i4] = o;
            xs += v.x + v.y + v.z + v.w;
            const float4* g4 = (const float4*)&gk[(size_t)i4 * 4 * NE];
#pragma unroll
            for (int j = 0; j < 4; ++j) {
                float xv = ((const float*)&v)[j];
                float4 ga = g4[j * 2], gc = g4[j * 2 + 1];
                acc[0] += xv * ga.x; acc[1] += xv * ga.y; acc[2] += xv * ga.z; acc[3] += xv * ga.w;
                acc[4] += xv * gc.x; acc[5] += xv * gc.y; acc[6] += xv * gc.z; acc[7] += xv * gc.w;
            }
        }
#pragma unroll
        for (int off = 32; off >= 1; off >>= 1) {
            xs += __shfl_xor(xs, off);
#pragma unroll
            for (int e = 0; e < 8; ++e) acc[e] += __shfl_xor(acc[e], off);
        }
        if (lane == 0) {
            float lg[8];
#pragma unroll
            for (int e = 0; e < 8; ++e) lg[e] = acc[e] + gb[e];
            int i1 = 0;
#pragma unroll
            for (int e = 1; e < 8; ++e) if (lg[e] > lg[i1]) i1 = e;  // first-occurrence argmax
            int i2 = (i1 == 0) ? 1 : 0;
#pragma unroll
            for (int e = 0; e < 8; ++e) {
                if (e == i1 || e == i2) continue;
                if (lg[e] > lg[i2]) i2 = e;
            }
            float p1 = 1.f / (1.f + expf(lg[i2] - lg[i1]));  // renorm top-2 softmax
            float p2 = 1.f - p1;
            xsum[b] = xs;
            pkb[b] = make_int4(i1, i2, __float_as_int(p1), __float_as_int(p2));
        }
    } else {
        int i = (bx - 3072) * 256 + tid;
        float r = rho[i];
        se[i] = log1pf(expf(r)) * eps[i];
    }
}

// ================= pairlist: compact rows per unordered expert pair (28 blocks) =================
__global__ __launch_bounds__(256) void pairlist_kernel(
    const int4* __restrict__ pkb, int* __restrict__ cnt,
    u16* __restrict__ plist)
{
    const int pid = blockIdx.x;
    int p = 0, rem = pid;                 // decode p<q triangular
    while (rem >= 7 - p) { rem -= 7 - p; ++p; }
    const int q = p + 1 + rem;

    const int tid = threadIdx.x;
    const int wv = tid >> 6, lane = tid & 63;
    __shared__ int wsum[4];
    __shared__ int sbase;
    if (tid == 0) sbase = 0;
    __syncthreads();
    u16* pl = plist + pid * PL_CAP;
    for (int chunk = 0; chunk < BDIM; chunk += 256) {
        int b = chunk + tid;
        int4 pk = pkb[b];
        int lo = min(pk.x, pk.y), hi = max(pk.x, pk.y);
        bool f = (lo == p) && (hi == q);
        unsigned long long m = __ballot(f);
        int prefix = __popcll(m & ((1ULL << lane) - 1ULL));
        if (lane == 0) wsum[wv] = __popcll(m);
        __syncthreads();
        int wbase = sbase;
        for (int w = 0; w < wv; ++w) wbase += wsum[w];
        if (f) pl[wbase + prefix] = (u16)b;
        __syncthreads();
        if (tid == 0) sbase += wsum[0] + wsum[1] + wsum[2] + wsum[3];
        __syncthreads();
    }
    int c = sbase;
    int pc = (c + 63) & ~63;
    for (int i = c + tid; i < pc; i += 256) pl[i] = (u16)0xFFFF;
    if (tid == 0) cnt[pid] = c;
}

// ================= pair GEMM: round-8 geometry, SINGLE-barrier pipeline =================
// 64 rows x 64 u-cols x BOTH experts; T2 both-sides XOR swizzle (conflicts 0);
// plain stores, no atomics. Change vs round 8: ONE s_barrier per K-step.
// STAGE for tile t+1 is issued AFTER the top-of-step barrier -> its DMA target
// buf[cur^1] was fully read (by all waves) before they reached this barrier, so
// the "done-reading" second barrier is redundant and removed. Per-wave vmcnt(0)
// covers own tile-t loads; the barrier makes residency collective.
__global__ __launch_bounds__(256, 3) void gemm_pair_kernel(
    const u16* __restrict__ Xb,      // [4096][1024] bf16
    const u16* __restrict__ Wt,      // [8192][1024] bf16, row n = u*8+e
    const int4* __restrict__ pkb,    // per-row (i1,i2,p1,p2)
    const float* __restrict__ xsum,  // [4096]
    const float* __restrict__ se,    // [8192]
    const float* __restrict__ biasv, // [8192]
    const int* __restrict__ cnt,     // [28]
    const u16* __restrict__ plist,   // [28][PL_CAP]
    float* __restrict__ y)           // [4096][1024]
{
    const int bid = blockIdx.x;
    const int ntile = bid & 15;       // 16 n-tiles of 64 cols
    const int t = bid >> 4;           // m-slot 0..MAX_MT-1
    int pid = 0, base = 0;
    for (; pid < NPAIR; ++pid) {
        int mt = (cnt[pid] + 63) >> 6;
        if (t < base + mt) break;
        base += mt;
    }
    if (pid >= NPAIR) return;
    const int m0 = (t - base) << 6;
    int p = 0, rem = pid;
    while (rem >= 7 - p) { rem -= 7 - p; ++p; }
    const int q = p + 1 + rem;
    const int u0 = ntile << 6;

    __shared__ u16 As[2][64 * 64];
    __shared__ u16 Bp[2][64 * 64];
    __shared__ u16 Bq[2][64 * 64];

    const int tid  = threadIdx.x;
    const int lane = tid & 63;
    const int wid  = tid >> 6;
    const int wm = wid >> 1, wn = wid & 1;
    const int l15 = lane & 15;
    const int l4  = lane >> 4;

    const u16* __restrict__ rowl = plist + pid * PL_CAP + m0;
    const int stg_off = tid * 8;        // linear LDS dest (u16)
    const int sc = (((tid & 7) ^ ((tid >> 3) & 7))) * 8;  // source-side swizzle

    const u16* aP[2];
    const u16* bpP[2];
    const u16* bqP[2];
#pragma unroll
    for (int it = 0; it < 2; ++it) {
        int r = it * 32 + (tid >> 3);
        int rid = rowl[r];
        if (rid == 0xFFFF) rid = 0;     // padded slot: any valid row
        aP[it]  = Xb + (size_t)rid * DDIM + sc;
        bpP[it] = Wt + ((size_t)(u0 + r) * NE + p) * DDIM + sc;
        bqP[it] = Wt + ((size_t)(u0 + r) * NE + q) * DDIM + sc;
    }

#define STAGE(BUF, KK) do {                                     \
        gload_lds16(aP[0]  + (KK), &As[BUF][stg_off]);          \
        gload_lds16(aP[1]  + (KK), &As[BUF][2048 + stg_off]);   \
        gload_lds16(bpP[0] + (KK), &Bp[BUF][stg_off]);          \
        gload_lds16(bpP[1] + (KK), &Bp[BUF][2048 + stg_off]);   \
        gload_lds16(bqP[0] + (KK), &Bq[BUF][stg_off]);          \
        gload_lds16(bqP[1] + (KK), &Bq[BUF][2048 + stg_off]);   \
    } while (0)

    f32x4 accp[2][2] = {};
    f32x4 accq[2][2] = {};

    STAGE(0, 0);                        // prologue: tile 0 only

    const int sw = l15 & 7;             // read-side swizzle key

#pragma unroll
    for (int t2 = 0; t2 < 16; ++t2) {
        const int cur = t2 & 1;
        asm volatile("s_waitcnt vmcnt(0)" ::: "memory");   // own tile-t2 loads landed
        __builtin_amdgcn_s_barrier();          // collective: tile t2 resident; buf[cur^1] free
        __builtin_amdgcn_sched_barrier(0);     // no ds_read hoisting above this
        if (t2 < 15) STAGE(cur ^ 1, (t2 + 1) * 64);  // DMA overlaps this step's compute
#pragma unroll
        for (int k2 = 0; k2 < 2; ++k2) {
            const int cx = ((k2 * 4 + l4) ^ sw) * 8;
            bf16x8 av[2], bpv[2], bqv[2];
#pragma unroll
            for (int m = 0; m < 2; ++m)
                av[m] = *(const bf16x8*)&As[cur][(wm * 32 + m * 16 + l15) * 64 + cx];
#pragma unroll
            for (int n = 0; n < 2; ++n) {
                bpv[n] = *(const bf16x8*)&Bp[cur][(wn * 32 + n * 16 + l15) * 64 + cx];
                bqv[n] = *(const bf16x8*)&Bq[cur][(wn * 32 + n * 16 + l15) * 64 + cx];
            }
#pragma unroll
            for (int m = 0; m < 2; ++m)
#pragma unroll
                for (int n = 0; n < 2; ++n) {
                    accp[m][n] = __builtin_amdgcn_mfma_f32_16x16x32_bf16(av[m], bpv[n], accp[m][n], 0, 0, 0);
                    accq[m][n] = __builtin_amdgcn_mfma_f32_16x16x32_bf16(av[m], bqv[n], accq[m][n], 0, 0, 0);
                }
        }
        __builtin_amdgcn_sched_barrier(0);     // reads complete inside this step span
    }
#undef STAGE

    // Epilogue: y[b,u] = wp*(dot_p + xs*se_p + bias_p) + wq*(dot_q + xs*se_q + bias_q)
    // C/D layout: col=lane&15 (u), row=(lane>>4)*4+jj.
    float sep_[2], seq_[2], bip_[2], biq_[2];
#pragma unroll
    for (int n = 0; n < 2; ++n) {
        int u = u0 + wn * 32 + n * 16 + l15;
        sep_[n] = se[u * NE + p];    seq_[n] = se[u * NE + q];
        bip_[n] = biasv[u * NE + p]; biq_[n] = biasv[u * NE + q];
    }
#pragma unroll
    for (int m = 0; m < 2; ++m) {
#pragma unroll
        for (int jj = 0; jj < 4; ++jj) {
            int r_loc = wm * 32 + m * 16 + l4 * 4 + jj;
            u16 b16 = rowl[r_loc];
            if (b16 == (u16)0xFFFF) continue;
            int b = (int)b16;
            int4 pk = pkb[b];
            float wp, wq;
            if (pk.x == p) { wp = __int_as_float(pk.z); wq = __int_as_float(pk.w); }
            else           { wp = __int_as_float(pk.w); wq = __int_as_float(pk.z); }
            float xs = xsum[b];
            float* yrow = &y[(size_t)b * UDIM];
#pragma unroll
            for (int n = 0; n < 2; ++n) {
                int u = u0 + wn * 32 + n * 16 + l15;
                float val = wp * (accp[m][n][jj] + xs * sep_[n] + bip_[n])
                          + wq * (accq[m][n][jj] + xs * seq_[n] + biq_[n]);
                yrow[u] = val;
            }
        }
    }
}

extern "C" void kernel_launch(void* const* d_in, const int* in_sizes, int n_in,
                              void* d_out, int out_size, void* d_ws, size_t ws_size,
                              hipStream_t stream) {
    const float* x    = (const float*)d_in[0];
    const float* mu   = (const float*)d_in[1];
    const float* rho  = (const float*)d_in[2];
    const float* bias = (const float*)d_in[3];
    const float* gk   = (const float*)d_in[4];
    const float* gb   = (const float*)d_in[5];
    const float* eps  = (const float*)d_in[6];
    float* y = (float*)d_out;

    char* ws = (char*)d_ws;
    u16*   Wt   = (u16*)ws;                       // 16,777,216
    u16*   xb   = (u16*)(ws + 16777216);          //  8,388,608 -> 25165824
    float* xsp  = (float*)(ws + 25165824);        //     16,384 -> 25182208
    float* sep  = (float*)(ws + 25182208);        //     32,768 -> 25214976
    int*   cnt  = (int*)(ws + 25214976);          //        128 -> 25215104
    int4*  pkb  = (int4*)(ws + 25215104);         //     65,536 -> 25280640
    u16*   prl  = (u16*)(ws + 25280640);          //    232,960 -> 25513600
    if (ws_size < 25513600) return;

    prep_kernel<<<dim3(3104), dim3(256), 0, stream>>>(
        mu, x, gk, gb, rho, eps, Wt, xb, xsp, pkb, sep);
    pairlist_kernel<<<dim3(NPAIR), dim3(256), 0, stream>>>(pkb, cnt, prl);
    gemm_pair_kernel<<<dim3(MAX_MT * 16), dim3(256), 0, stream>>>(
        xb, Wt, pkb, xsp, sep, bias, cnt, prl, y);
}

// Round 15
// 87.181 us; speedup vs baseline: 1.1371x; 1.0284x over previous
//
#include <hip/hip_runtime.h>
#include <hip/hip_bf16.h>

typedef unsigned short u16;
typedef __attribute__((ext_vector_type(8))) short bf16x8;
typedef __attribute__((ext_vector_type(4))) float f32x4;

#define BDIM 4096
#define DDIM 1024
#define UDIM 1024
#define NE 8
#define NDIM 8192    // U*E
#define NPAIR 28     // C(8,2) unordered expert pairs
#define PL_CAP 4160  // per-pair rowlist capacity (4096 + pad)
#define MAX_MT 92    // max total m-tiles: floor(4096/64) + 27 + 1

__device__ __forceinline__ u16 f2bf(float f) {
    unsigned int u = __float_as_uint(f);
    u += 0x7fffu + ((u >> 16) & 1u);   // round-to-nearest-even
    return (u16)(u >> 16);
}

__device__ __forceinline__ void gload_lds16(const u16* g, u16* lds) {
    __builtin_amdgcn_global_load_lds(
        (const __attribute__((address_space(1))) void*)g,
        (__attribute__((address_space(3))) void*)lds, 16, 0, 0);
}

// ================= prep (fused): mu->Wt transpose | gating + x->bf16 | se =================
__global__ __launch_bounds__(256) void prep_kernel(
    const float* __restrict__ mu, const float* __restrict__ x,
    const float* __restrict__ gk, const float* __restrict__ gb,
    const float* __restrict__ rho, const float* __restrict__ eps,
    u16* __restrict__ Wt, u16* __restrict__ xb,
    float* __restrict__ xsum, int4* __restrict__ pkb,
    float* __restrict__ se)
{
    __shared__ u16 tile[64 * 68];
    const int bx = blockIdx.x;
    const int tid = threadIdx.x;

    if (bx < 2048) {
        const int n0 = (bx & 127) << 6;
        const int d0 = (bx >> 7) << 6;
        const int nq = (tid & 15) << 2;
        const int dr = tid >> 4;             // 0..15
#pragma unroll
        for (int p = 0; p < 4; ++p) {
            int dl = p * 16 + dr;
            float4 v = *(const float4*)&mu[(size_t)(d0 + dl) * NDIM + n0 + nq];
            ushort4 o;
            o.x = f2bf(v.x); o.y = f2bf(v.y); o.z = f2bf(v.z); o.w = f2bf(v.w);
            *(uint2*)&tile[dl * 68 + nq] = *(uint2*)&o;   // ds_write_b64
        }
        __syncthreads();
#pragma unroll
        for (int issue = 0; issue < 2; ++issue) {
            int nloc = issue * 32 + (tid >> 3);
            int d8 = (tid & 7) * 8;
            uint4 o; u16* tp = (u16*)&o;
#pragma unroll
            for (int i = 0; i < 8; ++i) tp[i] = tile[(d8 + i) * 68 + nloc];
            *(uint4*)&Wt[(size_t)(n0 + nloc) * DDIM + d0 + d8] = o;
        }
    } else if (bx < 3072) {
        const int b = (bx - 2048) * 4 + (tid >> 6);
        const int lane = tid & 63;
        float acc[8] = {0.f,0.f,0.f,0.f,0.f,0.f,0.f,0.f};
        float xs = 0.f;
        const float4* x4 = (const float4*)&x[(size_t)b * DDIM];
        ushort4* xb4 = (ushort4*)&xb[(size_t)b * DDIM];
#pragma unroll
        for (int it = 0; it < 4; ++it) {
            int i4 = it * 64 + lane;
            float4 v = x4[i4];
            ushort4 o;
            o.x = f2bf(v.x); o.y = f2bf(v.y); o.z = f2bf(v.z); o.w = f2bf(v.w);
            xb4[i4] = o;
            xs += v.x + v.y + v.z + v.w;
            const float4* g4 = (const float4*)&gk[(size_t)i4 * 4 * NE];
#pragma unroll
            for (int j = 0; j < 4; ++j) {
                float xv = ((const float*)&v)[j];
                float4 ga = g4[j * 2], gc = g4[j * 2 + 1];
                acc[0] += xv * ga.x; acc[1] += xv * ga.y; acc[2] += xv * ga.z; acc[3] += xv * ga.w;
                acc[4] += xv * gc.x; acc[5] += xv * gc.y; acc[6] += xv * gc.z; acc[7] += xv * gc.w;
            }
        }
#pragma unroll
        for (int off = 32; off >= 1; off >>= 1) {
            xs += __shfl_xor(xs, off);
#pragma unroll
            for (int e = 0; e < 8; ++e) acc[e] += __shfl_xor(acc[e], off);
        }
        if (lane == 0) {
            float lg[8];
#pragma unroll
            for (int e = 0; e < 8; ++e) lg[e] = acc[e] + gb[e];
            int i1 = 0;
#pragma unroll
            for (int e = 1; e < 8; ++e) if (lg[e] > lg[i1]) i1 = e;  // first-occurrence argmax
            int i2 = (i1 == 0) ? 1 : 0;
#pragma unroll
            for (int e = 0; e < 8; ++e) {
                if (e == i1 || e == i2) continue;
                if (lg[e] > lg[i2]) i2 = e;
            }
            float p1 = 1.f / (1.f + expf(lg[i2] - lg[i1]));  // renorm top-2 softmax
            float p2 = 1.f - p1;
            xsum[b] = xs;
            pkb[b] = make_int4(i1, i2, __float_as_int(p1), __float_as_int(p2));
        }
    } else {
        int i = (bx - 3072) * 256 + tid;
        float r = rho[i];
        se[i] = log1pf(expf(r)) * eps[i];
    }
}

// ================= pairlist: compact rows per unordered expert pair (28 blocks) =================
__global__ __launch_bounds__(256) void pairlist_kernel(
    const int4* __restrict__ pkb, int* __restrict__ cnt,
    u16* __restrict__ plist)
{
    const int pid = blockIdx.x;
    int p = 0, rem = pid;                 // decode p<q triangular
    while (rem >= 7 - p) { rem -= 7 - p; ++p; }
    const int q = p + 1 + rem;

    const int tid = threadIdx.x;
    const int wv = tid >> 6, lane = tid & 63;
    __shared__ int wsum[4];
    __shared__ int sbase;
    if (tid == 0) sbase = 0;
    __syncthreads();
    u16* pl = plist + pid * PL_CAP;
    for (int chunk = 0; chunk < BDIM; chunk += 256) {
        int b = chunk + tid;
        int4 pk = pkb[b];
        int lo = min(pk.x, pk.y), hi = max(pk.x, pk.y);
        bool f = (lo == p) && (hi == q);
        unsigned long long m = __ballot(f);
        int prefix = __popcll(m & ((1ULL << lane) - 1ULL));
        if (lane == 0) wsum[wv] = __popcll(m);
        __syncthreads();
        int wbase = sbase;
        for (int w = 0; w < wv; ++w) wbase += wsum[w];
        if (f) pl[wbase + prefix] = (u16)b;
        __syncthreads();
        if (tid == 0) sbase += wsum[0] + wsum[1] + wsum[2] + wsum[3];
        __syncthreads();
    }
    int c = sbase;
    int pc = (c + 63) & ~63;
    for (int i = c + tid; i < pc; i += 256) pl[i] = (u16)0xFFFF;
    if (tid == 0) cnt[pid] = c;
}

// ================= pair GEMM: 64 rows x 64 u-cols x BOTH experts, plain stores =================
// Counted-vmcnt dbuf pipeline + T2 both-sides XOR swizzle (conflicts verified 0).
// Epilogue fuses rank-1 noise+bias term; every y[b,u] written exactly once -> NO atomics.
__global__ __launch_bounds__(256, 3) void gemm_pair_kernel(
    const u16* __restrict__ Xb,      // [4096][1024] bf16
    const u16* __restrict__ Wt,      // [8192][1024] bf16, row n = u*8+e
    const int4* __restrict__ pkb,    // per-row (i1,i2,p1,p2)
    const float* __restrict__ xsum,  // [4096]
    const float* __restrict__ se,    // [8192]
    const float* __restrict__ biasv, // [8192]
    const int* __restrict__ cnt,     // [28]
    const u16* __restrict__ plist,   // [28][PL_CAP]
    float* __restrict__ y)           // [4096][1024]
{
    const int bid = blockIdx.x;
    const int ntile = bid & 15;       // 16 n-tiles of 64 cols
    const int t = bid >> 4;           // m-slot 0..MAX_MT-1
    int pid = 0, base = 0;
    for (; pid < NPAIR; ++pid) {
        int mt = (cnt[pid] + 63) >> 6;
        if (t < base + mt) break;
        base += mt;
    }
    if (pid >= NPAIR) return;
    const int m0 = (t - base) << 6;
    int p = 0, rem = pid;
    while (rem >= 7 - p) { rem -= 7 - p; ++p; }
    const int q = p + 1 + rem;
    const int u0 = ntile << 6;

    __shared__ u16 As[2][64 * 64];
    __shared__ u16 Bp[2][64 * 64];
    __shared__ u16 Bq[2][64 * 64];

    const int tid  = threadIdx.x;
    const int lane = tid & 63;
    const int wid  = tid >> 6;
    const int wm = wid >> 1, wn = wid & 1;
    const int l15 = lane & 15;
    const int l4  = lane >> 4;

    const u16* __restrict__ rowl = plist + pid * PL_CAP + m0;
    const int stg_off = tid * 8;        // linear LDS dest (u16)
    const int sc = (((tid & 7) ^ ((tid >> 3) & 7))) * 8;  // source-side swizzle

    const u16* aP[2];
    const u16* bpP[2];
    const u16* bqP[2];
#pragma unroll
    for (int it = 0; it < 2; ++it) {
        int r = it * 32 + (tid >> 3);
        int rid = rowl[r];
        if (rid == 0xFFFF) rid = 0;     // padded slot: any valid row
        aP[it]  = Xb + (size_t)rid * DDIM + sc;
        bpP[it] = Wt + ((size_t)(u0 + r) * NE + p) * DDIM + sc;
        bqP[it] = Wt + ((size_t)(u0 + r) * NE + q) * DDIM + sc;
    }

#define STAGE(BUF, KK) do {                                     \
        gload_lds16(aP[0]  + (KK), &As[BUF][stg_off]);          \
        gload_lds16(aP[1]  + (KK), &As[BUF][2048 + stg_off]);   \
        gload_lds16(bpP[0] + (KK), &Bp[BUF][stg_off]);          \
        gload_lds16(bpP[1] + (KK), &Bp[BUF][2048 + stg_off]);   \
        gload_lds16(bqP[0] + (KK), &Bq[BUF][stg_off]);          \
        gload_lds16(bqP[1] + (KK), &Bq[BUF][2048 + stg_off]);   \
    } while (0)

    f32x4 accp[2][2] = {};
    f32x4 accq[2][2] = {};

    STAGE(0, 0);
    STAGE(1, 64);                       // 12 loads in flight

    const int sw = l15 & 7;             // read-side swizzle key

#pragma unroll
    for (int t2 = 0; t2 < 16; ++t2) {
        const int cur = t2 & 1;
        if (t2 < 15) asm volatile("s_waitcnt vmcnt(6)" ::: "memory");
        else         asm volatile("s_waitcnt vmcnt(0)" ::: "memory");
        __builtin_amdgcn_s_barrier();          // tile t2 resident
        __builtin_amdgcn_sched_barrier(0);
#pragma unroll
        for (int k2 = 0; k2 < 2; ++k2) {
            const int cx = ((k2 * 4 + l4) ^ sw) * 8;
            bf16x8 av[2], bpv[2], bqv[2];
#pragma unroll
            for (int m = 0; m < 2; ++m)
                av[m] = *(const bf16x8*)&As[cur][(wm * 32 + m * 16 + l15) * 64 + cx];
#pragma unroll
            for (int n = 0; n < 2; ++n) {
                bpv[n] = *(const bf16x8*)&Bp[cur][(wn * 32 + n * 16 + l15) * 64 + cx];
                bqv[n] = *(const bf16x8*)&Bq[cur][(wn * 32 + n * 16 + l15) * 64 + cx];
            }
#pragma unroll
            for (int m = 0; m < 2; ++m)
#pragma unroll
                for (int n = 0; n < 2; ++n) {
                    accp[m][n] = __builtin_amdgcn_mfma_f32_16x16x32_bf16(av[m], bpv[n], accp[m][n], 0, 0, 0);
                    accq[m][n] = __builtin_amdgcn_mfma_f32_16x16x32_bf16(av[m], bqv[n], accq[m][n], 0, 0, 0);
                }
        }
        __builtin_amdgcn_sched_barrier(0);
        __builtin_amdgcn_s_barrier();          // all waves done with buf[cur]
        if (t2 < 14) STAGE(cur, (t2 + 2) * 64);
    }
#undef STAGE

    // Epilogue: y[b,u] = wp*(dot_p + xs*se_p + bias_p) + wq*(dot_q + xs*se_q + bias_q)
    // C/D layout: col=lane&15 (u), row=(lane>>4)*4+jj.
    float sep_[2], seq_[2], bip_[2], biq_[2];
#pragma unroll
    for (int n = 0; n < 2; ++n) {
        int u = u0 + wn * 32 + n * 16 + l15;
        sep_[n] = se[u * NE + p];    seq_[n] = se[u * NE + q];
        bip_[n] = biasv[u * NE + p]; biq_[n] = biasv[u * NE + q];
    }
#pragma unroll
    for (int m = 0; m < 2; ++m) {
#pragma unroll
        for (int jj = 0; jj < 4; ++jj) {
            int r_loc = wm * 32 + m * 16 + l4 * 4 + jj;
            u16 b16 = rowl[r_loc];
            if (b16 == (u16)0xFFFF) continue;
            int b = (int)b16;
            int4 pk = pkb[b];
            float wp, wq;
            if (pk.x == p) { wp = __int_as_float(pk.z); wq = __int_as_float(pk.w); }
            else           { wp = __int_as_float(pk.w); wq = __int_as_float(pk.z); }
            float xs = xsum[b];
            float* yrow = &y[(size_t)b * UDIM];
#pragma unroll
            for (int n = 0; n < 2; ++n) {
                int u = u0 + wn * 32 + n * 16 + l15;
                float val = wp * (accp[m][n][jj] + xs * sep_[n] + bip_[n])
                          + wq * (accq[m][n][jj] + xs * seq_[n] + biq_[n]);
                yrow[u] = val;
            }
        }
    }
}

extern "C" void kernel_launch(void* const* d_in, const int* in_sizes, int n_in,
                              void* d_out, int out_size, void* d_ws, size_t ws_size,
                              hipStream_t stream) {
    const float* x    = (const float*)d_in[0];
    const float* mu   = (const float*)d_in[1];
    const float* rho  = (const float*)d_in[2];
    const float* bias = (const float*)d_in[3];
    const float* gk   = (const float*)d_in[4];
    const float* gb   = (const float*)d_in[5];
    const float* eps  = (const float*)d_in[6];
    float* y = (float*)d_out;

    char* ws = (char*)d_ws;
    u16*   Wt   = (u16*)ws;                       // 16,777,216
    u16*   xb   = (u16*)(ws + 16777216);          //  8,388,608 -> 25165824
    float* xsp  = (float*)(ws + 25165824);        //     16,384 -> 25182208
    float* sep  = (float*)(ws + 25182208);        //     32,768 -> 25214976
    int*   cnt  = (int*)(ws + 25214976);          //        128 -> 25215104
    int4*  pkb  = (int4*)(ws + 25215104);         //     65,536 -> 25280640
    u16*   prl  = (u16*)(ws + 25280640);          //    232,960 -> 25513600
    if (ws_size < 25513600) return;

    prep_kernel<<<dim3(3104), dim3(256), 0, stream>>>(
        mu, x, gk, gb, rho, eps, Wt, xb, xsp, pkb, sep);
    pairlist_kernel<<<dim3(NPAIR), dim3(256), 0, stream>>>(pkb, cnt, prl);
    gemm_pair_kernel<<<dim3(MAX_MT * 16), dim3(256), 0, stream>>>(
        xb, Wt, pkb, xsp, sep, bias, cnt, prl, y);
}